// Round 20
// baseline (690.563 us; speedup 1.0000x reference)
//
#include <hip/hip_runtime.h>
#include <hip/hip_bf16.h>
#include <math.h>

#define B_ 128
#define N_ 2048
#define D_ 512
#define H_ 512

#define NEG_BIG (-1.0e30f)

typedef unsigned int uint;
typedef unsigned short ushort;

// ws layout (float offsets)
#define WS_INP  0
#define WS_ATT  (WS_INP + B_*H_)          // 65536
#define WS_M    (WS_ATT + B_*N_)          // +262144  (fallback path only)
#define WS_FLAG (WS_M + B_*D_)            // +65536
#define WS_BP   393280                    // Bpack = 524288 ushort = 1MB
#define WS_U    655424                    // u[B][D] 65536 floats
#define WS_S    720960                    // s[B] 128 floats
#define WS_END  721088
#define WS_MID  655424

typedef __attribute__((ext_vector_type(4))) float  f32x4;
typedef __attribute__((ext_vector_type(8))) short  bf16x8;

union BF8 { unsigned short u[8]; bf16x8 v; };

__device__ __forceinline__ ushort f2bf(float x) {
    uint u = __float_as_uint(x);
    u = (u + 0x7fffu + ((u >> 16) & 1u)) >> 16;   // RNE; inputs finite
    return (ushort)u;
}
__device__ __forceinline__ float bf2f(ushort h) {
    return __uint_as_float(((uint)h) << 16);
}
__device__ __forceinline__ float fast_tanh(float x) {
    return 1.0f - 2.0f / (1.0f + __expf(2.0f * x));
}

// ---------------------------------------------------------------------------
// Fused prep: blocks 0-127 pack Wc; 128-383 inp = x@Wi^T+bi; 384 detect_mask;
// 385-641 (fused path only) zero u[B][D] and s[B].
__global__ __launch_bounds__(256) void prep_kernel(
        const float* __restrict__ Wc, ushort* __restrict__ Bp,
        const float* __restrict__ x, const float* __restrict__ Wi,
        const float* __restrict__ bi, float* __restrict__ inp,
        const uint* __restrict__ mask_raw, int* __restrict__ flag,
        float* __restrict__ gU) {
    const int bid = blockIdx.x;
    const int t   = threadIdx.x;

    if (bid < 128) {                       // ---- pack_wc ----
        int tid = bid * 256 + t;           // 32768 threads
        int lane = tid & 63;
        int fs   = tid >> 6;
        int hf = fs >> 4, ks = fs & 15;
        int h  = hf * 16 + (lane & 15);
        int k0 = ks * 32 + (lane >> 4) * 8;
        const float* src = Wc + (size_t)h * D_ + k0;
        BF8 hi, lo;
#pragma unroll
        for (int j = 0; j < 8; ++j) {
            float xv = src[j];
            hi.u[j] = f2bf(xv);
            lo.u[j] = f2bf(xv - bf2f(hi.u[j]));
        }
        *(bf16x8*)(Bp + (size_t)tid * 8)          = hi.v;
        *(bf16x8*)(Bp + 262144 + (size_t)tid * 8) = lo.v;
    } else if (bid < 384) {                // ---- linear: inp ----
        int idx = (bid - 128) * 256 + t;   // 65536
        int b = idx >> 9;
        int h = idx & (H_ - 1);
        const float4* ar = (const float4*)(x + (size_t)b * D_);
        const float4* wr = (const float4*)(Wi + (size_t)h * D_);
        float acc = 0.f;
#pragma unroll 4
        for (int d = 0; d < D_ / 4; ++d) {
            float4 av = ar[d], wv = wr[d];
            acc = fmaf(av.x, wv.x, acc);
            acc = fmaf(av.y, wv.y, acc);
            acc = fmaf(av.z, wv.z, acc);
            acc = fmaf(av.w, wv.w, acc);
        }
        inp[idx] = acc + bi[h];
    } else if (bid == 384) {               // ---- detect_mask (1 wave) ----
        if (t < 64) {
            uint v = mask_raw[t];
            unsigned long long m = __ballot(v <= 1u);
            if (t == 0) *flag = (m == ~0ull) ? 1 : 0;
        }
    } else {                               // ---- zero u,s (fused only) ----
        int idx = (bid - 385) * 256 + t;
        if (idx < B_ * D_ + B_) gU[idx] = 0.f;
    }
}

// ---------------------------------------------------------------------------
__global__ __launch_bounds__(256) void linear_kernel(
        const float* __restrict__ a, const float* __restrict__ W,
        const float* __restrict__ bias, float* __restrict__ out) {
    int idx = blockIdx.x * 256 + threadIdx.x;
    int b = idx >> 9;
    int h = idx & (H_ - 1);
    const float4* ar = (const float4*)(a + (size_t)b * D_);
    const float4* wr = (const float4*)(W + (size_t)h * D_);
    float acc = 0.f;
#pragma unroll 4
    for (int d = 0; d < D_ / 4; ++d) {
        float4 av = ar[d], wv = wr[d];
        acc = fmaf(av.x, wv.x, acc);
        acc = fmaf(av.y, wv.y, acc);
        acc = fmaf(av.z, wv.z, acc);
        acc = fmaf(av.w, wv.w, acc);
    }
    out[idx] = acc + bias[h];
}

// hidden[b][h] = (sum_d u[b][d]*W[h][d]) / s[b] + bias[h]
__global__ __launch_bounds__(256) void linear_scaled_kernel(
        const float* __restrict__ u, const float* __restrict__ W,
        const float* __restrict__ bias, const float* __restrict__ s,
        float* __restrict__ out) {
    int idx = blockIdx.x * 256 + threadIdx.x;
    int b = idx >> 9;
    int h = idx & (H_ - 1);
    const float4* ar = (const float4*)(u + (size_t)b * D_);
    const float4* wr = (const float4*)(W + (size_t)h * D_);
    float acc = 0.f;
#pragma unroll 4
    for (int d = 0; d < D_ / 4; ++d) {
        float4 av = ar[d], wv = wr[d];
        acc = fmaf(av.x, wv.x, acc);
        acc = fmaf(av.y, wv.y, acc);
        acc = fmaf(av.z, wv.z, acc);
        acc = fmaf(av.w, wv.w, acc);
    }
    out[idx] = acc / s[b] + bias[h];
}

// ---------------------------------------------------------------------------
// Split-bf16 3-product MFMA (r18 core, reverted from r19's regression).
// BM=128, full H=512, 1024 thr / 16 waves — NOW 2r x 8c: square 64x64 wave
// tile cuts per-wave LDS reads 20KB->16KB (B-fragment redundancy 4x->2x;
// 320->256 KB/CU/phase on the co-bottleneck LDS port). acc[4][4]=64 regs ->
// 4 waves/SIMD kept. A: 16B-write XOR-swizzled staging (512 stagers).
// B: DMA from L2-hot Bpack, dbuf 128KB. Fused exp-trick context-mix tail.
#define KP  32
#define NPH 16

#define DMA_B(p, bi) do {                                                       \
    _Pragma("unroll")                                                           \
    for (int i_ = 0; i_ < 4; ++i_) {                                            \
        int c_  = w * 4 + i_;                                                   \
        int hf_ = c_ & 31;                                                      \
        const ushort* g_ = Bp + (c_ >= 32 ? 262144 : 0)                         \
                         + (size_t)((hf_ << 4) + (p)) * 512 + lane * 8;         \
        ushort* l_ = (c_ >= 32 ? sBl[bi] : sBh[bi]) + hf_ * 512;                \
        __builtin_amdgcn_global_load_lds(                                       \
            (const __attribute__((address_space(1))) unsigned int*)g_,          \
            (__attribute__((address_space(3))) unsigned int*)l_, 16, 0, 0);     \
    }                                                                           \
} while (0)

// truncation split: hi = top16(x); lo = top16(x - bf2f(hi)); 16B writes
#define STAGE_A2(Ux, Wx, bi) do {                                               \
    uint h0_ = (Ux.y & 0xFFFF0000u) | (Ux.x >> 16);                             \
    uint h1_ = (Ux.w & 0xFFFF0000u) | (Ux.z >> 16);                             \
    uint h2_ = (Wx.y & 0xFFFF0000u) | (Wx.x >> 16);                             \
    uint h3_ = (Wx.w & 0xFFFF0000u) | (Wx.z >> 16);                             \
    float r0_ = __uint_as_float(Ux.x) - __uint_as_float(Ux.x & 0xFFFF0000u);    \
    float r1_ = __uint_as_float(Ux.y) - __uint_as_float(Ux.y & 0xFFFF0000u);    \
    float r2_ = __uint_as_float(Ux.z) - __uint_as_float(Ux.z & 0xFFFF0000u);    \
    float r3_ = __uint_as_float(Ux.w) - __uint_as_float(Ux.w & 0xFFFF0000u);    \
    float r4_ = __uint_as_float(Wx.x) - __uint_as_float(Wx.x & 0xFFFF0000u);    \
    float r5_ = __uint_as_float(Wx.y) - __uint_as_float(Wx.y & 0xFFFF0000u);    \
    float r6_ = __uint_as_float(Wx.z) - __uint_as_float(Wx.z & 0xFFFF0000u);    \
    float r7_ = __uint_as_float(Wx.w) - __uint_as_float(Wx.w & 0xFFFF0000u);    \
    uint l0_ = (__float_as_uint(r1_) & 0xFFFF0000u) | (__float_as_uint(r0_) >> 16); \
    uint l1_ = (__float_as_uint(r3_) & 0xFFFF0000u) | (__float_as_uint(r2_) >> 16); \
    uint l2_ = (__float_as_uint(r5_) & 0xFFFF0000u) | (__float_as_uint(r4_) >> 16); \
    uint l3_ = (__float_as_uint(r7_) & 0xFFFF0000u) | (__float_as_uint(r6_) >> 16); \
    *(uint4*)((char*)sAh[bi] + aw) = make_uint4(h0_, h1_, h2_, h3_);            \
    *(uint4*)((char*)sAl[bi] + aw) = make_uint4(l0_, l1_, l2_, l3_);            \
} while (0)

#define MM(a_, b_, c_) __builtin_amdgcn_mfma_f32_16x16x32_bf16(a_, b_, c_, 0, 0, 0)

__global__ __launch_bounds__(1024, 4) void att_mfma_kernel(
        const float* __restrict__ ctx, const ushort* __restrict__ Bp,
        const float* __restrict__ bc, const float* __restrict__ V,
        const float* __restrict__ inp, float* __restrict__ att,
        float* __restrict__ gU, float* __restrict__ gS, int fused) {
    __shared__ ushort sAh[2][4096];    // 16KB  [buf][rowfrag8][lane64][8]
    __shared__ ushort sAl[2][4096];    // 16KB
    __shared__ ushort sBh[2][16384];   // 64KB  [buf][hf32][lane64][8]
    __shared__ ushort sBl[2][16384];   // 64KB

    const int t    = threadIdx.x;
    const int lane = t & 63;
    const int w    = t >> 6;               // 0..15
    const int wr   = w >> 3;               // 64-row group (0..1)
    const int wc   = w & 7;                // 64-col group (0..7)
    const int g0   = blockIdx.x * 128;
    const int b    = g0 >> 11;             // uniform per block

    // A staging (512 stagers, 16B writes, XOR swizzle)
    const int srow = t >> 2;               // valid for t<512: 0..127
    const int skc  = t & 3;
    const float* gAs = ctx + (size_t)(g0 + srow) * D_ + skc * 8;
    unsigned aw = ((unsigned)(srow >> 4) << 10) | ((unsigned)skc << 8)
                | ((unsigned)(srow & 15) << 4);
    aw ^= ((aw >> 8) & 3u) << 4;
    const bool stager = (t < 512);

    // A fragment read offsets (bytes), same swizzle; rowfrag = wr*4+rf
    unsigned ar_[4];
#pragma unroll
    for (int rf = 0; rf < 4; ++rf) {
        unsigned o = ((unsigned)(wr * 4 + rf) << 10) | ((unsigned)lane << 4);
        o ^= ((o >> 8) & 3u) << 4;
        ar_[rf] = o;
    }

    f32x4 acc[4][4] = {};

    // prologue: A(0) + B(0)
    {
        uint4 U0, W0;
        if (stager) {
            U0 = *(const uint4*)(gAs);
            W0 = *(const uint4*)(gAs + 4);
        }
        DMA_B(0, 0);
        if (stager) STAGE_A2(U0, W0, 0);
        __syncthreads();
    }

    for (int p = 0; p < NPH; ++p) {
        const int buf = p & 1;
        const int pn  = (p + 1) & 15;      // uniform; last prefetch dead

        bf16x8 ah[4], al[4];
#pragma unroll
        for (int rf = 0; rf < 4; ++rf) {
            ah[rf] = *(const bf16x8*)((const char*)sAh[buf] + ar_[rf]);
            al[rf] = *(const bf16x8*)((const char*)sAl[buf] + ar_[rf]);
        }

        uint4 U, Wv;
        if (stager) {
            U  = *(const uint4*)(gAs + pn * KP);
            Wv = *(const uint4*)(gAs + pn * KP + 4);
        }
        DMA_B(pn, buf ^ 1);

        __builtin_amdgcn_s_setprio(1);
#pragma unroll
        for (int cf = 0; cf < 4; ++cf) {
            const int bo = (wc * 4 + cf) * 512 + lane * 8;
            bf16x8 bh = *(const bf16x8*)&sBh[buf][bo];
            bf16x8 bl = *(const bf16x8*)&sBl[buf][bo];
#pragma unroll
            for (int rf = 0; rf < 4; ++rf) {
                acc[rf][cf] = MM(ah[rf], bh, acc[rf][cf]);
                acc[rf][cf] = MM(ah[rf], bl, acc[rf][cf]);
                acc[rf][cf] = MM(al[rf], bh, acc[rf][cf]);
            }
        }
        __builtin_amdgcn_s_setprio(0);

        if (stager) STAGE_A2(U, Wv, buf ^ 1);
        __syncthreads();                   // drains DMA + lgkm (race-free)
    }

    // epilogue: tanh + V-weight + reduce.  C/D: col=lane&15, row=(lane>>4)*4+j
    float P[4][4] = {};
#pragma unroll
    for (int cf = 0; cf < 4; ++cf) {
        const int h = wc * 64 + cf * 16 + (lane & 15);
        const float sh = inp[b * H_ + h] + bc[h];
        const float vh = V[h];
#pragma unroll
        for (int rf = 0; rf < 4; ++rf)
#pragma unroll
            for (int j = 0; j < 4; ++j)
                P[rf][j] += vh * fast_tanh(acc[rf][cf][j] + sh);
    }
#pragma unroll
    for (int rf = 0; rf < 4; ++rf)
#pragma unroll
        for (int j = 0; j < 4; ++j) {
            float x = P[rf][j];
            x += __shfl_xor(x, 1); x += __shfl_xor(x, 2);
            x += __shfl_xor(x, 4); x += __shfl_xor(x, 8);
            P[rf][j] = x;
        }

    float (*red)[64] = (float(*)[64])sAh;   // 4KB overlay (A dead)
    float* eV = (float*)sAl;                // 512B overlay
    if ((lane & 15) == 0) {
        const int kc = lane >> 4;
#pragma unroll
        for (int rf = 0; rf < 4; ++rf)
#pragma unroll
            for (int j = 0; j < 4; ++j)
                red[w][rf * 16 + kc * 4 + j] = P[rf][j];
    }
    __syncthreads();
    if (t < 128) {
        const int wr2 = t >> 6, r = t & 63;  // row within 64-row group
        const int wb = wr2 * 8;
        float av = red[wb + 0][r] + red[wb + 1][r] + red[wb + 2][r]
                 + red[wb + 3][r] + red[wb + 4][r] + red[wb + 5][r]
                 + red[wb + 6][r] + red[wb + 7][r];
        att[g0 + t] = av;
        eV[t] = __expf(av);                // exp-trick weight (no max-subtract)
    }
    __syncthreads();

    if (fused) {
        // u[b][d] += sum over this block's 128 rows of e[r]*ctx[row][d]
        const int d    = t & 511;
        const int half = t >> 9;           // rows half*64 .. half*64+63
        const float* cp = ctx + (size_t)(g0 + half * 64) * D_ + d;
        const float* ep = eV + half * 64;
        float acc0 = 0.f;
#pragma unroll 8
        for (int i = 0; i < 64; ++i)
            acc0 = fmaf(ep[i], cp[(size_t)i * D_], acc0);
        atomicAdd(&gU[b * D_ + d], acc0);
        if (t < 64) {
            float sp = eV[t] + eV[64 + t];
            sp += __shfl_xor(sp, 1); sp += __shfl_xor(sp, 2);
            sp += __shfl_xor(sp, 4); sp += __shfl_xor(sp, 8);
            sp += __shfl_xor(sp, 16); sp += __shfl_xor(sp, 32);
            if (t == 0) atomicAdd(&gS[b], sp);
        }
    }
}

// ---------------------------------------------------------------------------
__global__ __launch_bounds__(256) void softmax_kernel(
        const float* __restrict__ att, const void* __restrict__ mask,
        const int* __restrict__ flag, float* __restrict__ alpha,
        float* __restrict__ logp) {
    __shared__ float row[N_];
    __shared__ float red[4];
    const int b = blockIdx.x, t = threadIdx.x;
    const int is_int = *flag;
    const int* mi = (const int*)mask;
    const unsigned char* mb = (const unsigned char*)mask;

    float lmax = -INFINITY;
    for (int n = t; n < N_; n += 256) {
        bool m = is_int ? (mi[b * N_ + n] != 0) : (mb[b * N_ + n] != 0);
        float a = m ? NEG_BIG : att[b * N_ + n];
        row[n] = a;
        lmax = fmaxf(lmax, a);
    }
#pragma unroll
    for (int off = 32; off; off >>= 1) lmax = fmaxf(lmax, __shfl_down(lmax, off));
    if ((t & 63) == 0) red[t >> 6] = lmax;
    __syncthreads();
    const float rmax = fmaxf(fmaxf(red[0], red[1]), fmaxf(red[2], red[3]));
    __syncthreads();

    float lsum = 0.f;
    for (int n = t; n < N_; n += 256) lsum += __expf(row[n] - rmax);
#pragma unroll
    for (int off = 32; off; off >>= 1) lsum += __shfl_down(lsum, off);
    if ((t & 63) == 0) red[t >> 6] = lsum;
    __syncthreads();
    const float s = red[0] + red[1] + red[2] + red[3];
    const float inv = 1.0f / s;
    const float lse = logf(s);

    for (int n = t; n < N_; n += 256) {
        float a = row[n];
        alpha[b * N_ + n] = __expf(a - rmax) * inv;
        logp[b * N_ + n]  = a - rmax - lse;
    }
}

// ---------------------------------------------------------------------------
// Fallback path only (ws too small for fused u/s).
__global__ __launch_bounds__(512) void wsum_kernel(
        const float* __restrict__ context, const float* __restrict__ alpha,
        float* __restrict__ m) {
    __shared__ float al[N_];
    __shared__ float part[3][128];
    const int c = blockIdx.x;
    const int b = blockIdx.y;
    const int t = threadIdx.x;
    for (int n = t; n < N_; n += 512) al[n] = alpha[(size_t)b * N_ + n];
    __syncthreads();
    const int d = c * 128 + (t & 127);
    const int q = t >> 7;
    const float* cp = context + (size_t)b * N_ * D_ + (size_t)q * 512 * D_ + d;
    const float* ap = al + q * 512;
    float acc = 0.f;
#pragma unroll 8
    for (int n = 0; n < 512; ++n) acc = fmaf(ap[n], cp[(size_t)n * D_], acc);
    if (q) part[q - 1][t & 127] = acc;
    __syncthreads();
    if (q == 0)
        m[b * D_ + d] = acc + part[0][t & 127] + part[1][t & 127] + part[2][t & 127];
}

// ---------------------------------------------------------------------------
extern "C" void kernel_launch(void* const* d_in, const int* in_sizes, int n_in,
                              void* d_out, int out_size, void* d_ws, size_t ws_size,
                              hipStream_t stream) {
    const float* x       = (const float*)d_in[0];
    const float* context = (const float*)d_in[1];
    const void*  mask    = d_in[2];
    const float* Wi      = (const float*)d_in[3];
    const float* bi      = (const float*)d_in[4];
    const float* Wc      = (const float*)d_in[5];
    const float* bc      = (const float*)d_in[6];
    const float* V       = (const float*)d_in[7];

    float* out  = (float*)d_out;
    float* ws   = (float*)d_ws;
    float* inp  = ws + WS_INP;
    float* att  = ws + WS_ATT;
    float* m    = ws + WS_M;
    int*   flag = (int*)(ws + WS_FLAG);
    float* gU   = ws + WS_U;
    float* gS   = ws + WS_S;

    float* hidden = out;
    float* alpha  = out + B_ * H_;
    float* logp   = alpha + B_ * N_;

    const bool fused = (ws_size >= (size_t)WS_END * 4);
    const bool bp_ws = (ws_size >= (size_t)(WS_MID + 262144) * 4);
    ushort* Bp = bp_ws ? (ushort*)(ws + WS_BP) : (ushort*)logp;

    prep_kernel<<<fused ? 642 : 385, 256, 0, stream>>>(
        Wc, Bp, x, Wi, bi, inp, (const uint*)mask, flag, gU);
    att_mfma_kernel<<<(B_ * N_) / 128, 1024, 0, stream>>>(
        context, Bp, bc, V, inp, att, gU, gS, fused ? 1 : 0);
    softmax_kernel<<<B_, 256, 0, stream>>>(att, mask, flag, alpha, logp);
    if (fused) {
        linear_scaled_kernel<<<256, 256, 0, stream>>>(gU, Wc, bc, gS, hidden);
    } else {
        wsum_kernel<<<dim3(4, B_), 512, 0, stream>>>(context, alpha, m);
        linear_kernel<<<256, 256, 0, stream>>>(m, Wc, bc, hidden);
    }
}

// Round 21
// 498.604 us; speedup vs baseline: 1.3850x; 1.3850x over previous
//
#include <hip/hip_runtime.h>
#include <hip/hip_bf16.h>
#include <math.h>

#define B_ 128
#define N_ 2048
#define D_ 512
#define H_ 512

#define NEG_BIG (-1.0e30f)

typedef unsigned int uint;
typedef unsigned short ushort;

// ws layout (float offsets)
#define WS_INP  0
#define WS_ATT  (WS_INP + B_*H_)          // 65536
#define WS_M    (WS_ATT + B_*N_)          // +262144  (fallback path only)
#define WS_FLAG (WS_M + B_*D_)            // +65536
#define WS_BP   393280                    // Bpack = 524288 ushort = 1MB
#define WS_U    655424                    // u[B][D] 65536 floats
#define WS_S    720960                    // s[B] 128 floats
#define WS_END  721088
#define WS_MID  655424

typedef __attribute__((ext_vector_type(4))) float  f32x4;
typedef __attribute__((ext_vector_type(8))) short  bf16x8;

union BF8 { unsigned short u[8]; bf16x8 v; };

__device__ __forceinline__ ushort f2bf(float x) {
    uint u = __float_as_uint(x);
    u = (u + 0x7fffu + ((u >> 16) & 1u)) >> 16;   // RNE; inputs finite
    return (ushort)u;
}
__device__ __forceinline__ float bf2f(ushort h) {
    return __uint_as_float(((uint)h) << 16);
}
__device__ __forceinline__ float fast_tanh(float x) {
    return 1.0f - 2.0f / (1.0f + __expf(2.0f * x));
}

// ---------------------------------------------------------------------------
// Fused prep: blocks 0-127 pack Wc; 128-383 inp = x@Wi^T+bi; 384 detect_mask;
// 385-641 (fused path only) zero u[B][D] and s[B].
__global__ __launch_bounds__(256) void prep_kernel(
        const float* __restrict__ Wc, ushort* __restrict__ Bp,
        const float* __restrict__ x, const float* __restrict__ Wi,
        const float* __restrict__ bi, float* __restrict__ inp,
        const uint* __restrict__ mask_raw, int* __restrict__ flag,
        float* __restrict__ gU) {
    const int bid = blockIdx.x;
    const int t   = threadIdx.x;

    if (bid < 128) {                       // ---- pack_wc ----
        int tid = bid * 256 + t;           // 32768 threads
        int lane = tid & 63;
        int fs   = tid >> 6;
        int hf = fs >> 4, ks = fs & 15;
        int h  = hf * 16 + (lane & 15);
        int k0 = ks * 32 + (lane >> 4) * 8;
        const float* src = Wc + (size_t)h * D_ + k0;
        BF8 hi, lo;
#pragma unroll
        for (int j = 0; j < 8; ++j) {
            float xv = src[j];
            hi.u[j] = f2bf(xv);
            lo.u[j] = f2bf(xv - bf2f(hi.u[j]));
        }
        *(bf16x8*)(Bp + (size_t)tid * 8)          = hi.v;
        *(bf16x8*)(Bp + 262144 + (size_t)tid * 8) = lo.v;
    } else if (bid < 384) {                // ---- linear: inp ----
        int idx = (bid - 128) * 256 + t;   // 65536
        int b = idx >> 9;
        int h = idx & (H_ - 1);
        const float4* ar = (const float4*)(x + (size_t)b * D_);
        const float4* wr = (const float4*)(Wi + (size_t)h * D_);
        float acc = 0.f;
#pragma unroll 4
        for (int d = 0; d < D_ / 4; ++d) {
            float4 av = ar[d], wv = wr[d];
            acc = fmaf(av.x, wv.x, acc);
            acc = fmaf(av.y, wv.y, acc);
            acc = fmaf(av.z, wv.z, acc);
            acc = fmaf(av.w, wv.w, acc);
        }
        inp[idx] = acc + bi[h];
    } else if (bid == 384) {               // ---- detect_mask (1 wave) ----
        if (t < 64) {
            uint v = mask_raw[t];
            unsigned long long m = __ballot(v <= 1u);
            if (t == 0) *flag = (m == ~0ull) ? 1 : 0;
        }
    } else {                               // ---- zero u,s (fused only) ----
        int idx = (bid - 385) * 256 + t;
        if (idx < B_ * D_ + B_) gU[idx] = 0.f;
    }
}

// ---------------------------------------------------------------------------
__global__ __launch_bounds__(256) void linear_kernel(
        const float* __restrict__ a, const float* __restrict__ W,
        const float* __restrict__ bias, float* __restrict__ out) {
    int idx = blockIdx.x * 256 + threadIdx.x;
    int b = idx >> 9;
    int h = idx & (H_ - 1);
    const float4* ar = (const float4*)(a + (size_t)b * D_);
    const float4* wr = (const float4*)(W + (size_t)h * D_);
    float acc = 0.f;
#pragma unroll 4
    for (int d = 0; d < D_ / 4; ++d) {
        float4 av = ar[d], wv = wr[d];
        acc = fmaf(av.x, wv.x, acc);
        acc = fmaf(av.y, wv.y, acc);
        acc = fmaf(av.z, wv.z, acc);
        acc = fmaf(av.w, wv.w, acc);
    }
    out[idx] = acc + bias[h];
}

// hidden[b][h] = (sum_d u[b][d]*W[h][d]) / s[b] + bias[h]
__global__ __launch_bounds__(256) void linear_scaled_kernel(
        const float* __restrict__ u, const float* __restrict__ W,
        const float* __restrict__ bias, const float* __restrict__ s,
        float* __restrict__ out) {
    int idx = blockIdx.x * 256 + threadIdx.x;
    int b = idx >> 9;
    int h = idx & (H_ - 1);
    const float4* ar = (const float4*)(u + (size_t)b * D_);
    const float4* wr = (const float4*)(W + (size_t)h * D_);
    float acc = 0.f;
#pragma unroll 4
    for (int d = 0; d < D_ / 4; ++d) {
        float4 av = ar[d], wv = wr[d];
        acc = fmaf(av.x, wv.x, acc);
        acc = fmaf(av.y, wv.y, acc);
        acc = fmaf(av.z, wv.z, acc);
        acc = fmaf(av.w, wv.w, acc);
    }
    out[idx] = acc / s[b] + bias[h];
}

// ---------------------------------------------------------------------------
// Split-bf16 3-product MFMA (r16 core + fused exp-trick tail; measured best:
// att 463us, total 501us). BM=128, full H=512, 1024 thr / 16 waves (4r x 4c);
// wave tile 32x128, acc[2][8]=64 AGPR -> 4 waves/SIMD. A: 16B-write
// XOR-swizzled staging (512 stagers). B: DMA from L2-hot Bpack, dbuf 128KB.
// FUSED TAIL: u[b][d] += sum_r exp(att_r)*ctx[r][d] (kills the 536MB wsum).
#define KP  32
#define NPH 16

#define DMA_B(p, bi) do {                                                       \
    _Pragma("unroll")                                                           \
    for (int i_ = 0; i_ < 4; ++i_) {                                            \
        int c_  = w * 4 + i_;                                                   \
        int hf_ = c_ & 31;                                                      \
        const ushort* g_ = Bp + (c_ >= 32 ? 262144 : 0)                         \
                         + (size_t)((hf_ << 4) + (p)) * 512 + lane * 8;         \
        ushort* l_ = (c_ >= 32 ? sBl[bi] : sBh[bi]) + hf_ * 512;                \
        __builtin_amdgcn_global_load_lds(                                       \
            (const __attribute__((address_space(1))) unsigned int*)g_,          \
            (__attribute__((address_space(3))) unsigned int*)l_, 16, 0, 0);     \
    }                                                                           \
} while (0)

// truncation split: hi = top16(x); lo = top16(x - bf2f(hi)); 16B writes
#define STAGE_A2(Ux, Wx, bi) do {                                               \
    uint h0_ = (Ux.y & 0xFFFF0000u) | (Ux.x >> 16);                             \
    uint h1_ = (Ux.w & 0xFFFF0000u) | (Ux.z >> 16);                             \
    uint h2_ = (Wx.y & 0xFFFF0000u) | (Wx.x >> 16);                             \
    uint h3_ = (Wx.w & 0xFFFF0000u) | (Wx.z >> 16);                             \
    float r0_ = __uint_as_float(Ux.x) - __uint_as_float(Ux.x & 0xFFFF0000u);    \
    float r1_ = __uint_as_float(Ux.y) - __uint_as_float(Ux.y & 0xFFFF0000u);    \
    float r2_ = __uint_as_float(Ux.z) - __uint_as_float(Ux.z & 0xFFFF0000u);    \
    float r3_ = __uint_as_float(Ux.w) - __uint_as_float(Ux.w & 0xFFFF0000u);    \
    float r4_ = __uint_as_float(Wx.x) - __uint_as_float(Wx.x & 0xFFFF0000u);    \
    float r5_ = __uint_as_float(Wx.y) - __uint_as_float(Wx.y & 0xFFFF0000u);    \
    float r6_ = __uint_as_float(Wx.z) - __uint_as_float(Wx.z & 0xFFFF0000u);    \
    float r7_ = __uint_as_float(Wx.w) - __uint_as_float(Wx.w & 0xFFFF0000u);    \
    uint l0_ = (__float_as_uint(r1_) & 0xFFFF0000u) | (__float_as_uint(r0_) >> 16); \
    uint l1_ = (__float_as_uint(r3_) & 0xFFFF0000u) | (__float_as_uint(r2_) >> 16); \
    uint l2_ = (__float_as_uint(r5_) & 0xFFFF0000u) | (__float_as_uint(r4_) >> 16); \
    uint l3_ = (__float_as_uint(r7_) & 0xFFFF0000u) | (__float_as_uint(r6_) >> 16); \
    *(uint4*)((char*)sAh[bi] + aw) = make_uint4(h0_, h1_, h2_, h3_);            \
    *(uint4*)((char*)sAl[bi] + aw) = make_uint4(l0_, l1_, l2_, l3_);            \
} while (0)

#define MM(a_, b_, c_) __builtin_amdgcn_mfma_f32_16x16x32_bf16(a_, b_, c_, 0, 0, 0)

__global__ __launch_bounds__(1024, 4) void att_mfma_kernel(
        const float* __restrict__ ctx, const ushort* __restrict__ Bp,
        const float* __restrict__ bc, const float* __restrict__ V,
        const float* __restrict__ inp, float* __restrict__ att,
        float* __restrict__ gU, float* __restrict__ gS, int fused) {
    __shared__ ushort sAh[2][4096];    // 16KB  [buf][rowfrag8][lane64][8]
    __shared__ ushort sAl[2][4096];    // 16KB
    __shared__ ushort sBh[2][16384];   // 64KB  [buf][hf32][lane64][8]
    __shared__ ushort sBl[2][16384];   // 64KB

    const int t    = threadIdx.x;
    const int lane = t & 63;
    const int w    = t >> 6;               // 0..15
    const int wr   = w >> 2;               // 32-row group
    const int wc   = w & 3;                // 128-col group
    const int g0   = blockIdx.x * 128;
    const int b    = g0 >> 11;             // uniform per block

    // A staging (512 stagers, 16B writes, XOR swizzle)
    const int srow = t >> 2;               // valid for t<512: 0..127
    const int skc  = t & 3;
    const float* gAs = ctx + (size_t)(g0 + srow) * D_ + skc * 8;
    unsigned aw = ((unsigned)(srow >> 4) << 10) | ((unsigned)skc << 8)
                | ((unsigned)(srow & 15) << 4);
    aw ^= ((aw >> 8) & 3u) << 4;
    const bool stager = (t < 512);

    // A fragment read offsets (bytes), same swizzle; rowfrag = wr*2+rf
    unsigned ar0 = ((unsigned)(wr * 2 + 0) << 10) | ((unsigned)lane << 4);
    ar0 ^= ((ar0 >> 8) & 3u) << 4;
    unsigned ar1 = ((unsigned)(wr * 2 + 1) << 10) | ((unsigned)lane << 4);
    ar1 ^= ((ar1 >> 8) & 3u) << 4;

    f32x4 acc[2][8] = {};

    // prologue: A(0) + B(0)
    {
        uint4 U0, W0;
        if (stager) {
            U0 = *(const uint4*)(gAs);
            W0 = *(const uint4*)(gAs + 4);
        }
        DMA_B(0, 0);
        if (stager) STAGE_A2(U0, W0, 0);
        __syncthreads();
    }

    for (int p = 0; p < NPH; ++p) {
        const int buf = p & 1;
        const int pn  = (p + 1) & 15;      // uniform; last prefetch dead

        bf16x8 ah0 = *(const bf16x8*)((const char*)sAh[buf] + ar0);
        bf16x8 al0 = *(const bf16x8*)((const char*)sAl[buf] + ar0);
        bf16x8 ah1 = *(const bf16x8*)((const char*)sAh[buf] + ar1);
        bf16x8 al1 = *(const bf16x8*)((const char*)sAl[buf] + ar1);

        uint4 U, Wv;
        if (stager) {
            U  = *(const uint4*)(gAs + pn * KP);
            Wv = *(const uint4*)(gAs + pn * KP + 4);
        }
        DMA_B(pn, buf ^ 1);

        __builtin_amdgcn_s_setprio(1);
#pragma unroll
        for (int cf = 0; cf < 8; ++cf) {
            const int bo = (wc * 8 + cf) * 512 + lane * 8;
            bf16x8 bh = *(const bf16x8*)&sBh[buf][bo];
            bf16x8 bl = *(const bf16x8*)&sBl[buf][bo];
            acc[0][cf] = MM(ah0, bh, acc[0][cf]);
            acc[1][cf] = MM(ah1, bh, acc[1][cf]);
            acc[0][cf] = MM(ah0, bl, acc[0][cf]);
            acc[1][cf] = MM(ah1, bl, acc[1][cf]);
            acc[0][cf] = MM(al0, bh, acc[0][cf]);
            acc[1][cf] = MM(al1, bh, acc[1][cf]);
        }
        __builtin_amdgcn_s_setprio(0);

        if (stager) STAGE_A2(U, Wv, buf ^ 1);
        __syncthreads();                   // drains DMA + lgkm (race-free)
    }

    // epilogue: tanh + V-weight + reduce.  C/D: col=lane&15, row=(lane>>4)*4+j
    float P[2][4] = {};
#pragma unroll
    for (int cf = 0; cf < 8; ++cf) {
        const int h = wc * 128 + cf * 16 + (lane & 15);
        const float sh = inp[b * H_ + h] + bc[h];
        const float vh = V[h];
#pragma unroll
        for (int rf = 0; rf < 2; ++rf)
#pragma unroll
            for (int j = 0; j < 4; ++j)
                P[rf][j] += vh * fast_tanh(acc[rf][cf][j] + sh);
    }
#pragma unroll
    for (int rf = 0; rf < 2; ++rf)
#pragma unroll
        for (int j = 0; j < 4; ++j) {
            float x = P[rf][j];
            x += __shfl_xor(x, 1); x += __shfl_xor(x, 2);
            x += __shfl_xor(x, 4); x += __shfl_xor(x, 8);
            P[rf][j] = x;
        }

    float (*red)[32] = (float(*)[32])sAh;   // 2KB overlay (A dead)
    float* eV = (float*)sAl;                // 512B overlay
    if ((lane & 15) == 0) {
        const int kc = lane >> 4;
#pragma unroll
        for (int rf = 0; rf < 2; ++rf)
#pragma unroll
            for (int j = 0; j < 4; ++j)
                red[w][rf * 16 + kc * 4 + j] = P[rf][j];
    }
    __syncthreads();
    if (t < 128) {
        const int wr2 = t >> 5, r = t & 31;
        float av = red[wr2 * 4 + 0][r] + red[wr2 * 4 + 1][r]
                 + red[wr2 * 4 + 2][r] + red[wr2 * 4 + 3][r];
        att[g0 + t] = av;
        eV[t] = __expf(av);                // exp-trick weight (no max-subtract)
    }
    __syncthreads();

    if (fused) {
        // u[b][d] += sum over this block's 128 rows of e[r]*ctx[row][d]
        const int d    = t & 511;
        const int half = t >> 9;           // rows half*64 .. half*64+63
        const float* cp = ctx + (size_t)(g0 + half * 64) * D_ + d;
        const float* ep = eV + half * 64;
        float acc0 = 0.f;
#pragma unroll 8
        for (int i = 0; i < 64; ++i)
            acc0 = fmaf(ep[i], cp[(size_t)i * D_], acc0);
        atomicAdd(&gU[b * D_ + d], acc0);
        if (t < 64) {
            float sp = eV[t] + eV[64 + t];
            sp += __shfl_xor(sp, 1); sp += __shfl_xor(sp, 2);
            sp += __shfl_xor(sp, 4); sp += __shfl_xor(sp, 8);
            sp += __shfl_xor(sp, 16); sp += __shfl_xor(sp, 32);
            if (t == 0) atomicAdd(&gS[b], sp);
        }
    }
}

// ---------------------------------------------------------------------------
__global__ __launch_bounds__(256) void softmax_kernel(
        const float* __restrict__ att, const void* __restrict__ mask,
        const int* __restrict__ flag, float* __restrict__ alpha,
        float* __restrict__ logp) {
    __shared__ float row[N_];
    __shared__ float red[4];
    const int b = blockIdx.x, t = threadIdx.x;
    const int is_int = *flag;
    const int* mi = (const int*)mask;
    const unsigned char* mb = (const unsigned char*)mask;

    float lmax = -INFINITY;
    for (int n = t; n < N_; n += 256) {
        bool m = is_int ? (mi[b * N_ + n] != 0) : (mb[b * N_ + n] != 0);
        float a = m ? NEG_BIG : att[b * N_ + n];
        row[n] = a;
        lmax = fmaxf(lmax, a);
    }
#pragma unroll
    for (int off = 32; off; off >>= 1) lmax = fmaxf(lmax, __shfl_down(lmax, off));
    if ((t & 63) == 0) red[t >> 6] = lmax;
    __syncthreads();
    const float rmax = fmaxf(fmaxf(red[0], red[1]), fmaxf(red[2], red[3]));
    __syncthreads();

    float lsum = 0.f;
    for (int n = t; n < N_; n += 256) lsum += __expf(row[n] - rmax);
#pragma unroll
    for (int off = 32; off; off >>= 1) lsum += __shfl_down(lsum, off);
    if ((t & 63) == 0) red[t >> 6] = lsum;
    __syncthreads();
    const float s = red[0] + red[1] + red[2] + red[3];
    const float inv = 1.0f / s;
    const float lse = logf(s);

    for (int n = t; n < N_; n += 256) {
        float a = row[n];
        alpha[b * N_ + n] = __expf(a - rmax) * inv;
        logp[b * N_ + n]  = a - rmax - lse;
    }
}

// ---------------------------------------------------------------------------
// Fallback path only (ws too small for fused u/s).
__global__ __launch_bounds__(512) void wsum_kernel(
        const float* __restrict__ context, const float* __restrict__ alpha,
        float* __restrict__ m) {
    __shared__ float al[N_];
    __shared__ float part[3][128];
    const int c = blockIdx.x;
    const int b = blockIdx.y;
    const int t = threadIdx.x;
    for (int n = t; n < N_; n += 512) al[n] = alpha[(size_t)b * N_ + n];
    __syncthreads();
    const int d = c * 128 + (t & 127);
    const int q = t >> 7;
    const float* cp = context + (size_t)b * N_ * D_ + (size_t)q * 512 * D_ + d;
    const float* ap = al + q * 512;
    float acc = 0.f;
#pragma unroll 8
    for (int n = 0; n < 512; ++n) acc = fmaf(ap[n], cp[(size_t)n * D_], acc);
    if (q) part[q - 1][t & 127] = acc;
    __syncthreads();
    if (q == 0)
        m[b * D_ + d] = acc + part[0][t & 127] + part[1][t & 127] + part[2][t & 127];
}

// ---------------------------------------------------------------------------
extern "C" void kernel_launch(void* const* d_in, const int* in_sizes, int n_in,
                              void* d_out, int out_size, void* d_ws, size_t ws_size,
                              hipStream_t stream) {
    const float* x       = (const float*)d_in[0];
    const float* context = (const float*)d_in[1];
    const void*  mask    = d_in[2];
    const float* Wi      = (const float*)d_in[3];
    const float* bi      = (const float*)d_in[4];
    const float* Wc      = (const float*)d_in[5];
    const float* bc      = (const float*)d_in[6];
    const float* V       = (const float*)d_in[7];

    float* out  = (float*)d_out;
    float* ws   = (float*)d_ws;
    float* inp  = ws + WS_INP;
    float* att  = ws + WS_ATT;
    float* m    = ws + WS_M;
    int*   flag = (int*)(ws + WS_FLAG);
    float* gU   = ws + WS_U;
    float* gS   = ws + WS_S;

    float* hidden = out;
    float* alpha  = out + B_ * H_;
    float* logp   = alpha + B_ * N_;

    const bool fused = (ws_size >= (size_t)WS_END * 4);
    const bool bp_ws = (ws_size >= (size_t)(WS_MID + 262144) * 4);
    ushort* Bp = bp_ws ? (ushort*)(ws + WS_BP) : (ushort*)logp;

    prep_kernel<<<fused ? 642 : 385, 256, 0, stream>>>(
        Wc, Bp, x, Wi, bi, inp, (const uint*)mask, flag, gU);
    att_mfma_kernel<<<(B_ * N_) / 128, 1024, 0, stream>>>(
        context, Bp, bc, V, inp, att, gU, gS, fused ? 1 : 0);
    softmax_kernel<<<B_, 256, 0, stream>>>(att, mask, flag, alpha, logp);
    if (fused) {
        linear_scaled_kernel<<<256, 256, 0, stream>>>(gU, Wc, bc, gS, hidden);
    } else {
        wsum_kernel<<<dim3(4, B_), 512, 0, stream>>>(context, alpha, m);
        linear_kernel<<<256, 256, 0, stream>>>(m, Wc, bc, hidden);
    }
}